// Round 4
// baseline (122.991 us; speedup 1.0000x reference)
//
#include <hip/hip_runtime.h>
#include <hip/hip_bf16.h>

// out[b,n] = prod_d psi((x[b,d]-c[n,d])/s[n,d]),  psi(z)=(1-z^2)exp(-z^2/2)
// Factorization: prod psi = [prod(1-z^2)] * exp(-0.5*sum z^2) per 16-d group
// (avoids fp32 overflow: |1-z^2|^8 per packed lane ~1.8e15, product at group
// end ~3e30 < 3.4e38 for |z|<=9; data |z| < 9).
//
// R4: deterministic memory paths.
//  - params pp[dp*N+n] = {cp0,cp1,rs0,rs1} staged to LDS (4 KB/block) once,
//    inner reads are ds_read_b128 at wave-uniform addresses -> broadcast.
//  - x transposed to xp[dp*B+b] float2 pairs -> fully coalesced dwordx2.
//  - BPT=2 b-rows/thread: 2048 pk-inst vs 256 ds_read per wave.
//  - packed fp32 (v_pk_*) via ext_vector_type(2).
// R2 lesson: (256,8) forced VGPR=32 + scratch spill (169 MB writes). Need
// ~110 VGPR -> (256,4).

#define DD 64
#define NT 8            // n columns per block
#define BPT 2           // b rows per thread
#define BB (256 * BPT)  // 512 b rows per block

typedef float v2f __attribute__((ext_vector_type(2)));

__global__ __launch_bounds__(256)
void prep(const float* __restrict__ x, const float* __restrict__ c,
          const float* __restrict__ s, float4* __restrict__ pp,
          float2* __restrict__ xp, int B, int N) {
    int i = blockIdx.x * 256 + threadIdx.x;
    int nxp = B * (DD / 2);                 // x-transpose records
    if (i < nxp) {
        int dp = i / B, b = i - dp * B;     // write-coalesced
        xp[i] = make_float2(x[b * DD + 2 * dp], x[b * DD + 2 * dp + 1]);
    } else {
        int k = i - nxp;                    // param records: (DD/2)*N
        if (k < (DD / 2) * N) {
            int dp = k / N, n = k - dp * N;
            float r0 = 1.0f / s[n * DD + 2 * dp];
            float r1 = 1.0f / s[n * DD + 2 * dp + 1];
            pp[k] = make_float4(c[n * DD + 2 * dp] * r0,
                                c[n * DD + 2 * dp + 1] * r1, r0, r1);
        }
    }
}

__global__ __launch_bounds__(256, 4)
void wavelet_kernel(const float2* __restrict__ xp,
                    const float4* __restrict__ pp,
                    float* __restrict__ out, int B, int N) {
    __shared__ float4 prm[(DD / 2) * NT];   // 32 dp x 8 n = 4 KB

    int t = threadIdx.x;
    int n0 = blockIdx.y * NT;
    int b0 = blockIdx.x * BB;

    // stage params: one float4 per thread
    {
        int dp = t >> 3, j = t & 7;
        prm[dp * NT + j] = pp[dp * N + n0 + j];
    }
    __syncthreads();

    int bA = b0 + t;          // row 0
    int bB = bA + 256;        // row 1

    float acc[BPT][NT];
#pragma unroll
    for (int r = 0; r < BPT; ++r)
#pragma unroll
        for (int j = 0; j < NT; ++j) acc[r][j] = 1.0f;

#pragma unroll
    for (int g = 0; g < 4; ++g) {           // 4 groups of 16 d (8 d-pairs)
        v2f p[BPT][NT], s2[BPT][NT];
#pragma unroll
        for (int r = 0; r < BPT; ++r)
#pragma unroll
            for (int j = 0; j < NT; ++j) {
                p[r][j]  = (v2f){1.0f, 1.0f};
                s2[r][j] = (v2f){0.0f, 0.0f};
            }

#pragma unroll
        for (int dq = 0; dq < 8; ++dq) {
            int dp = g * 8 + dq;
            float2 xa = xp[(size_t)dp * B + bA];   // coalesced dwordx2
            float2 xb = xp[(size_t)dp * B + bB];
            v2f x0 = {xa.x, xa.y};
            v2f x1 = {xb.x, xb.y};
#pragma unroll
            for (int j = 0; j < NT; ++j) {
                float4 q = prm[dp * NT + j];       // uniform -> LDS broadcast
                v2f cp = {q.x, q.y};
                v2f rs = {q.z, q.w};

                v2f z0 = __builtin_elementwise_fma(x0, rs, -cp);
                v2f w0 = z0 * z0;
                p[0][j] = __builtin_elementwise_fma(-w0, p[0][j], p[0][j]);
                s2[0][j] += w0;

                v2f z1 = __builtin_elementwise_fma(x1, rs, -cp);
                v2f w1 = z1 * z1;
                p[1][j] = __builtin_elementwise_fma(-w1, p[1][j], p[1][j]);
                s2[1][j] += w1;
            }
        }

#pragma unroll
        for (int r = 0; r < BPT; ++r)
#pragma unroll
            for (int j = 0; j < NT; ++j) {  // one exp per 16-d group
                float pr = p[r][j].x * p[r][j].y;
                float sr = s2[r][j].x + s2[r][j].y;
                acc[r][j] *= pr * __expf(-0.5f * sr);
            }
    }

    // 32 B contiguous per row
#pragma unroll
    for (int r = 0; r < BPT; ++r) {
        int b = (r == 0) ? bA : bB;
        float4* op = (float4*)(out + (size_t)b * N + n0);
        op[0] = make_float4(acc[r][0], acc[r][1], acc[r][2], acc[r][3]);
        op[1] = make_float4(acc[r][4], acc[r][5], acc[r][6], acc[r][7]);
    }
}

extern "C" void kernel_launch(void* const* d_in, const int* in_sizes, int n_in,
                              void* d_out, int out_size, void* d_ws, size_t ws_size,
                              hipStream_t stream) {
    const float* x = (const float*)d_in[0];
    const float* c = (const float*)d_in[1];
    const float* s = (const float*)d_in[2];
    float* out = (float*)d_out;

    int B = in_sizes[0] / DD;    // 8192
    int N = in_sizes[1] / DD;    // 512

    float4* pp = (float4*)d_ws;                            // 256 KB
    float2* xp = (float2*)((char*)d_ws + (size_t)(DD / 2) * N * 16);  // 2 MB

    int total = B * (DD / 2) + (DD / 2) * N;
    prep<<<(total + 255) / 256, 256, 0, stream>>>(x, c, s, pp, xp, B, N);

    dim3 grid(B / BB, N / NT);   // 16 x 64 = 1024 blocks
    wavelet_kernel<<<grid, 256, 0, stream>>>(xp, pp, out, B, N);
}

// Round 5
// 97.789 us; speedup vs baseline: 1.2577x; 1.2577x over previous
//
#include <hip/hip_runtime.h>
#include <hip/hip_bf16.h>

// out[b,n] = prod_d psi((x[b,d]-c[n,d])/s[n,d]),  psi(z)=(1-z^2)exp(-z^2/2)
// Factorization: prod psi = [prod(1-z^2)] * exp(-0.5*sum z^2) per 16-d group
// (avoids fp32 overflow: per-group |prod(1-z^2)| <= ~80^16 ~ 3e30 < 3.4e38
// for |z|<=9; data |z| < 9).
//
// Structure (R4): params pp[dp*N+n]={cp0,cp1,rs0,rs1} staged to 4 KB LDS,
// inner reads wave-uniform ds_read_b128 -> broadcast; x transposed to
// xp[dp*B+b] float2 -> coalesced dwordx2; BPT=2 rows/thread; packed fp32
// (v_pk_fma_f32) via ext_vector_type(2).
//
// LAUNCH BOUNDS RULE (measured R1/R2/R4): on this toolchain the 2nd arg w
// caps VGPRs at 256/w (NOT 512/w): w=8 -> VGPR 32 (R2, spilled), w=4 ->
// VGPR 64 (R4, spilled: WRITE_SIZE 151 MB). This kernel needs ~110 VGPRs
// -> w=2 (cap 128). HW occupancy at ~110-128 VGPR is 4 waves/SIMD (512
// pool), one full generation of 1024 blocks.

#define DD 64
#define NT 8            // n columns per block
#define BPT 2           // b rows per thread
#define BB (256 * BPT)  // 512 b rows per block

typedef float v2f __attribute__((ext_vector_type(2)));

__global__ __launch_bounds__(256)
void prep(const float* __restrict__ x, const float* __restrict__ c,
          const float* __restrict__ s, float4* __restrict__ pp,
          float2* __restrict__ xp, int B, int N) {
    int i = blockIdx.x * 256 + threadIdx.x;
    int nxp = B * (DD / 2);                 // x-transpose records
    if (i < nxp) {
        int dp = i / B, b = i - dp * B;     // write-coalesced
        xp[i] = make_float2(x[b * DD + 2 * dp], x[b * DD + 2 * dp + 1]);
    } else {
        int k = i - nxp;                    // param records: (DD/2)*N
        if (k < (DD / 2) * N) {
            int dp = k / N, n = k - dp * N;
            float r0 = 1.0f / s[n * DD + 2 * dp];
            float r1 = 1.0f / s[n * DD + 2 * dp + 1];
            pp[k] = make_float4(c[n * DD + 2 * dp] * r0,
                                c[n * DD + 2 * dp + 1] * r1, r0, r1);
        }
    }
}

__global__ __launch_bounds__(256, 2)
void wavelet_kernel(const float2* __restrict__ xp,
                    const float4* __restrict__ pp,
                    float* __restrict__ out, int B, int N) {
    __shared__ float4 prm[(DD / 2) * NT];   // 32 dp x 8 n = 4 KB

    int t = threadIdx.x;
    int n0 = blockIdx.y * NT;
    int b0 = blockIdx.x * BB;

    // stage params: one float4 per thread
    {
        int dp = t >> 3, j = t & 7;
        prm[dp * NT + j] = pp[dp * N + n0 + j];
    }
    __syncthreads();

    int bA = b0 + t;          // row 0
    int bB = bA + 256;        // row 1

    float acc[BPT][NT];
#pragma unroll
    for (int r = 0; r < BPT; ++r)
#pragma unroll
        for (int j = 0; j < NT; ++j) acc[r][j] = 1.0f;

#pragma unroll
    for (int g = 0; g < 4; ++g) {           // 4 groups of 16 d (8 d-pairs)
        v2f p[BPT][NT], s2[BPT][NT];
#pragma unroll
        for (int r = 0; r < BPT; ++r)
#pragma unroll
            for (int j = 0; j < NT; ++j) {
                p[r][j]  = (v2f){1.0f, 1.0f};
                s2[r][j] = (v2f){0.0f, 0.0f};
            }

#pragma unroll
        for (int dq = 0; dq < 8; ++dq) {
            int dp = g * 8 + dq;
            float2 xa = xp[(size_t)dp * B + bA];   // coalesced dwordx2
            float2 xb = xp[(size_t)dp * B + bB];
            v2f x0 = {xa.x, xa.y};
            v2f x1 = {xb.x, xb.y};
#pragma unroll
            for (int j = 0; j < NT; ++j) {
                float4 q = prm[dp * NT + j];       // uniform -> LDS broadcast
                v2f cp = {q.x, q.y};
                v2f rs = {q.z, q.w};

                v2f z0 = __builtin_elementwise_fma(x0, rs, -cp);
                v2f w0 = z0 * z0;
                p[0][j] = __builtin_elementwise_fma(-w0, p[0][j], p[0][j]);
                s2[0][j] += w0;

                v2f z1 = __builtin_elementwise_fma(x1, rs, -cp);
                v2f w1 = z1 * z1;
                p[1][j] = __builtin_elementwise_fma(-w1, p[1][j], p[1][j]);
                s2[1][j] += w1;
            }
        }

#pragma unroll
        for (int r = 0; r < BPT; ++r)
#pragma unroll
            for (int j = 0; j < NT; ++j) {  // one exp2 per 16-d group
                float pr = p[r][j].x * p[r][j].y;
                float sr = s2[r][j].x + s2[r][j].y;
                // exp(-0.5*sr) = exp2(-0.72134752*sr)
                acc[r][j] *= pr * __builtin_exp2f(-0.72134752f * sr);
            }
    }

    // 32 B contiguous per row
#pragma unroll
    for (int r = 0; r < BPT; ++r) {
        int b = (r == 0) ? bA : bB;
        float4* op = (float4*)(out + (size_t)b * N + n0);
        op[0] = make_float4(acc[r][0], acc[r][1], acc[r][2], acc[r][3]);
        op[1] = make_float4(acc[r][4], acc[r][5], acc[r][6], acc[r][7]);
    }
}

extern "C" void kernel_launch(void* const* d_in, const int* in_sizes, int n_in,
                              void* d_out, int out_size, void* d_ws, size_t ws_size,
                              hipStream_t stream) {
    const float* x = (const float*)d_in[0];
    const float* c = (const float*)d_in[1];
    const float* s = (const float*)d_in[2];
    float* out = (float*)d_out;

    int B = in_sizes[0] / DD;    // 8192
    int N = in_sizes[1] / DD;    // 512

    float4* pp = (float4*)d_ws;                            // 256 KB
    float2* xp = (float2*)((char*)d_ws + (size_t)(DD / 2) * N * 16);  // 2 MB

    int total = B * (DD / 2) + (DD / 2) * N;
    prep<<<(total + 255) / 256, 256, 0, stream>>>(x, c, s, pp, xp, B, N);

    dim3 grid(B / BB, N / NT);   // 16 x 64 = 1024 blocks
    wavelet_kernel<<<grid, 256, 0, stream>>>(xp, pp, out, B, N);
}

// Round 6
// 95.667 us; speedup vs baseline: 1.2856x; 1.0222x over previous
//
#include <hip/hip_runtime.h>
#include <hip/hip_bf16.h>

// out[b,n] = prod_d psi((x[b,d]-c[n,d])/s[n,d]),  psi(z)=(1-z^2)exp(-z^2/2)
// Factorization: prod psi = [prod(1-z^2)] * exp(-0.5*sum z^2) per 16-d group
// (per-lane partial product <= 80^8 ~ 1.7e15, merged ~3e30 < 3.4e38).
//
// R6: latency-amortized structure. g-outer loop: batch-load the 16-d x
// group for BPT=2 rows into registers (16 coalesced dwordx2, ONE latency
// window per ~2000 cyc of math — R5 exposed an L2 latency every dq).
// Params in 4 KB LDS, ds_read_b128 at wave-uniform address (broadcast);
// each read feeds 64 pk-inst. v_pk_fma_f32 does NOT double fp32 rate
// (157 TF spec is scalar rate) — packing only compacts inst count.
//
// Launch-bounds rule (measured R2/R4/R5): 2nd arg w caps VGPR at 256/w.
// Need ~80-100 VGPR -> w=2 (cap 128). VGPR<=128 -> 4 waves/SIMD (m69),
// grid 1024 blocks = 4 blocks/CU, one co-resident generation, no tail.

#define DD 64
#define NT 8            // n columns per block
#define BPT 2           // b rows per thread
#define BB (256 * BPT)  // 512 b rows per block

typedef float v2f __attribute__((ext_vector_type(2)));

__global__ __launch_bounds__(256)
void prep(const float* __restrict__ x, const float* __restrict__ c,
          const float* __restrict__ s, float4* __restrict__ pp,
          float2* __restrict__ xp, int B, int N) {
    int i = blockIdx.x * 256 + threadIdx.x;
    int nxp = B * (DD / 2);                 // x-transpose records
    if (i < nxp) {
        int dp = i / B, b = i - dp * B;     // write-coalesced
        xp[i] = make_float2(x[b * DD + 2 * dp], x[b * DD + 2 * dp + 1]);
    } else {
        int k = i - nxp;                    // param records: (DD/2)*N
        if (k < (DD / 2) * N) {
            int dp = k / N, n = k - dp * N;
            float r0 = 1.0f / s[n * DD + 2 * dp];
            float r1 = 1.0f / s[n * DD + 2 * dp + 1];
            pp[k] = make_float4(c[n * DD + 2 * dp] * r0,
                                c[n * DD + 2 * dp + 1] * r1, r0, r1);
        }
    }
}

__global__ __launch_bounds__(256, 2)
void wavelet_kernel(const float2* __restrict__ xp,
                    const float4* __restrict__ pp,
                    float* __restrict__ out, int B, int N) {
    __shared__ float4 prm[(DD / 2) * NT];   // [dp][j], 32x8 float4 = 4 KB

    int t = threadIdx.x;
    int n0 = blockIdx.y * NT;
    int b0 = blockIdx.x * BB;

    {   // stage params: one float4 per thread (256 = 32 dp x 8 j exactly)
        int dp = t >> 3, j = t & 7;
        prm[dp * NT + j] = pp[dp * N + n0 + j];
    }
    __syncthreads();

    int bA = b0 + t;
    int bB = bA + 256;

    float acc0[NT], acc1[NT];
#pragma unroll
    for (int j = 0; j < NT; ++j) { acc0[j] = 1.0f; acc1[j] = 1.0f; }

#pragma unroll
    for (int g = 0; g < 4; ++g) {           // 4 groups of 16 d (8 d-pairs)
        // batch x loads for this group: ONE latency window per group
        v2f xr0[8], xr1[8];
#pragma unroll
        for (int dp = 0; dp < 8; ++dp) {
            float2 a = xp[(size_t)(g * 8 + dp) * B + bA];
            float2 c2 = xp[(size_t)(g * 8 + dp) * B + bB];
            xr0[dp] = (v2f){a.x, a.y};
            xr1[dp] = (v2f){c2.x, c2.y};
        }

#pragma unroll
        for (int j = 0; j < NT; ++j) {
            v2f p0 = {1.0f, 1.0f}, p1 = {1.0f, 1.0f};
            v2f s0 = {0.0f, 0.0f}, s1 = {0.0f, 0.0f};
#pragma unroll
            for (int dp = 0; dp < 8; ++dp) {
                float4 q = prm[(g * 8 + dp) * NT + j];  // uniform -> broadcast
                v2f cp = {q.x, q.y};
                v2f rs = {q.z, q.w};

                v2f z0 = __builtin_elementwise_fma(xr0[dp], rs, -cp);
                v2f w0 = z0 * z0;
                p0 = __builtin_elementwise_fma(-w0, p0, p0);
                s0 += w0;

                v2f z1 = __builtin_elementwise_fma(xr1[dp], rs, -cp);
                v2f w1 = z1 * z1;
                p1 = __builtin_elementwise_fma(-w1, p1, p1);
                s1 += w1;
            }
            // one exp2 per 16-d group: exp(-0.5*s) = exp2(-0.72134752*s)
            acc0[j] *= (p0.x * p0.y) * __builtin_exp2f(-0.72134752f * (s0.x + s0.y));
            acc1[j] *= (p1.x * p1.y) * __builtin_exp2f(-0.72134752f * (s1.x + s1.y));
        }
    }

    // 32 B contiguous per row
    {
        float4* opA = (float4*)(out + (size_t)bA * N + n0);
        opA[0] = make_float4(acc0[0], acc0[1], acc0[2], acc0[3]);
        opA[1] = make_float4(acc0[4], acc0[5], acc0[6], acc0[7]);
        float4* opB = (float4*)(out + (size_t)bB * N + n0);
        opB[0] = make_float4(acc1[0], acc1[1], acc1[2], acc1[3]);
        opB[1] = make_float4(acc1[4], acc1[5], acc1[6], acc1[7]);
    }
}

extern "C" void kernel_launch(void* const* d_in, const int* in_sizes, int n_in,
                              void* d_out, int out_size, void* d_ws, size_t ws_size,
                              hipStream_t stream) {
    const float* x = (const float*)d_in[0];
    const float* c = (const float*)d_in[1];
    const float* s = (const float*)d_in[2];
    float* out = (float*)d_out;

    int B = in_sizes[0] / DD;    // 8192
    int N = in_sizes[1] / DD;    // 512

    float4* pp = (float4*)d_ws;                            // 256 KB
    float2* xp = (float2*)((char*)d_ws + (size_t)(DD / 2) * N * 16);  // 2 MB

    int total = B * (DD / 2) + (DD / 2) * N;
    prep<<<(total + 255) / 256, 256, 0, stream>>>(x, c, s, pp, xp, B, N);

    dim3 grid(B / BB, N / NT);   // 16 x 64 = 1024 blocks
    wavelet_kernel<<<grid, 256, 0, stream>>>(xp, pp, out, B, N);
}

// Round 7
// 87.722 us; speedup vs baseline: 1.4021x; 1.0906x over previous
//
#include <hip/hip_runtime.h>
#include <hip/hip_bf16.h>

// out[b,n] = prod_d psi((x[b,d]-c[n,d])/s[n,d]),  psi(z)=(1-z^2)exp(-z^2/2)
// Factorization: prod psi = [prod(1-z^2)] * exp(-0.5*sum z^2) per 16-d group
// (per-lane partial product <= 80^8 ~ 1.7e15, merged ~3e30 < 3.4e38 fp32 max).
//
// R7: lane = n column, wave = 16-row b-strip.
//  - params pp[dp*N+n]={cp0,cp1,rs0,rs1}: lane-private coalesced dwordx4,
//    VGPR-RESIDENT per 32-d half (64 VGPRs), reused across 16 b rows.
//    -> no LDS, no __syncthreads, no ds_read latency chain.
//  - x addresses wave-uniform (readfirstlane) -> one cache line per wave
//    load, L1/L2-hit; no x transpose needed (prep computes pp only).
//  - stores: lanes = consecutive n -> coalesced dwords.
// Issue floor: 2048 v_pk ops/wave x 4 cyc x 4 waves/SIMD ~ 13.7 us.
//
// Launch-bounds rule (measured R2/R4/R5): 2nd arg w caps VGPR at 256/w.
// Need ~114 -> w=2 (cap 128). 128 VGPR -> 4 waves/SIMD; grid 1024 blocks
// = 4 blocks/CU, one co-resident generation, no tail.

#define DD 64
#define BSTRIP 16   // b rows per wave

typedef float v2f __attribute__((ext_vector_type(2)));

__global__ __launch_bounds__(256)
void prep(const float* __restrict__ c, const float* __restrict__ s,
          float4* __restrict__ pp, int N) {
    int i = blockIdx.x * 256 + threadIdx.x;   // over (DD/2)*N
    if (i < (DD / 2) * N) {
        int dp = i / N, n = i - dp * N;
        float r0 = 1.0f / s[n * DD + 2 * dp];
        float r1 = 1.0f / s[n * DD + 2 * dp + 1];
        pp[i] = make_float4(c[n * DD + 2 * dp] * r0,
                            c[n * DD + 2 * dp + 1] * r1, r0, r1);
    }
}

__global__ __launch_bounds__(256, 2)
void wavelet_kernel(const float* __restrict__ x,
                    const float4* __restrict__ pp,
                    float* __restrict__ out, int B, int N) {
    int t = threadIdx.x;
    int lane = t & 63;
    int wv = __builtin_amdgcn_readfirstlane(t >> 6);   // wave-uniform
    int n = blockIdx.y * 64 + lane;                    // lane-private column
    int b0 = (blockIdx.x * 4 + wv) * BSTRIP;           // wave-uniform strip

    const float4* pcol = pp + n;   // pp[dp*N + n], lane-coalesced

    float acc[BSTRIP];
#pragma unroll
    for (int bi = 0; bi < BSTRIP; ++bi) acc[bi] = 1.0f;

#pragma unroll
    for (int h = 0; h < 2; ++h) {          // d-halves of 32
        // params for this half: VGPR-resident, reused by all 16 b rows
        v2f cp[16], rs[16];
#pragma unroll
        for (int i = 0; i < 16; ++i) {
            float4 q = pcol[(size_t)(h * 16 + i) * N];  // coalesced dwordx4
            cp[i] = (v2f){q.x, q.y};
            rs[i] = (v2f){q.z, q.w};
        }

#pragma unroll
        for (int bi = 0; bi < BSTRIP; ++bi) {
            // x row slice: wave-uniform address -> one line per load
            const float4* xq =
                (const float4*)(x + (size_t)(b0 + bi) * DD + h * 32);
            float a = acc[bi];
#pragma unroll
            for (int g2 = 0; g2 < 2; ++g2) {           // 16-d overflow groups
                float4 X0 = xq[g2 * 4 + 0];
                float4 X1 = xq[g2 * 4 + 1];
                float4 X2 = xq[g2 * 4 + 2];
                float4 X3 = xq[g2 * 4 + 3];
                float xs[16] = {X0.x, X0.y, X0.z, X0.w,
                                X1.x, X1.y, X1.z, X1.w,
                                X2.x, X2.y, X2.z, X2.w,
                                X3.x, X3.y, X3.z, X3.w};
                v2f p  = {1.0f, 1.0f};
                v2f s2 = {0.0f, 0.0f};
#pragma unroll
                for (int k = 0; k < 8; ++k) {          // 8 d-pairs
                    int dpi = g2 * 8 + k;
                    v2f xv = {xs[2 * k], xs[2 * k + 1]};  // uniform scalar pair
                    v2f z = __builtin_elementwise_fma(xv, rs[dpi], -cp[dpi]);
                    v2f w = z * z;
                    p = __builtin_elementwise_fma(-w, p, p);
                    s2 += w;
                }
                // exp(-0.5*s) = exp2(-0.72134752*s), one per 16-d group
                a *= (p.x * p.y) *
                     __builtin_exp2f(-0.72134752f * (s2.x + s2.y));
            }
            acc[bi] = a;
        }
    }

    // stores: lanes = consecutive n -> coalesced
#pragma unroll
    for (int bi = 0; bi < BSTRIP; ++bi)
        out[(size_t)(b0 + bi) * N + n] = acc[bi];
}

extern "C" void kernel_launch(void* const* d_in, const int* in_sizes, int n_in,
                              void* d_out, int out_size, void* d_ws, size_t ws_size,
                              hipStream_t stream) {
    const float* x = (const float*)d_in[0];
    const float* c = (const float*)d_in[1];
    const float* s = (const float*)d_in[2];
    float* out = (float*)d_out;

    int B = in_sizes[0] / DD;    // 8192
    int N = in_sizes[1] / DD;    // 512

    float4* pp = (float4*)d_ws;  // (DD/2)*N*16 B = 256 KB

    int total = (DD / 2) * N;
    prep<<<(total + 255) / 256, 256, 0, stream>>>(c, s, pp, N);

    // grid: x = b-strip groups (4 waves/block), y = n-tiles of 64
    dim3 grid(B / (4 * BSTRIP), N / 64);   // 128 x 8 = 1024 blocks
    wavelet_kernel<<<grid, 256, 0, stream>>>(x, pp, out, B, N);
}

// Round 8
// 83.928 us; speedup vs baseline: 1.4654x; 1.0452x over previous
//
#include <hip/hip_runtime.h>
#include <hip/hip_bf16.h>

// out[b,n] = prod_d psi((x[b,d]-c[n,d])/s[n,d]),  psi(z)=(1-z^2)exp(-z^2/2)
// Factorization: prod psi = [prod(1-z^2)] * exp(-0.5*sum z^2) per 16-d group
// (per-lane partial product <= 80^8 ~ 1.7e15, merged ~3e30 < 3.4e38 fp32 max).
// fp32-only: any f16 path puts ~1e-3 rel error into the exponent -> output
// scales by e^0.064, 11 orders above the 1.7e-18 absmax threshold.
//
// R8: R7's lane=n layout + occupancy play. BSTRIP 16->8, param residency
// 32d->16d (cp/rs = 32 VGPRs) to fit the <=64-VGPR occupancy cliff ->
// 8 waves/SIMD (vs 4). x loads wave-uniform -> scalar path; stores
// lane-coalesced. VALU issue floor ~13.7 us (536M pk-inst / 1024 SIMD
// x 4 cyc; v_pk_fma_f32 does NOT double the 157 TF fp32 rate).
//
// Launch-bounds rule (measured R2/R4/R5): 2nd arg w caps VGPR at 256/w.
// w=4 -> cap 64. Budget: params 32 + acc 8 + temps ~16 = ~56. If this
// spills (WRITE_SIZE >> 50 MB), revert to R7.

#define DD 64
#define BSTRIP 8    // b rows per wave

typedef float v2f __attribute__((ext_vector_type(2)));

__global__ __launch_bounds__(256)
void prep(const float* __restrict__ c, const float* __restrict__ s,
          float4* __restrict__ pp, int N) {
    int i = blockIdx.x * 256 + threadIdx.x;   // over (DD/2)*N
    if (i < (DD / 2) * N) {
        int dp = i / N, n = i - dp * N;
        float r0 = 1.0f / s[n * DD + 2 * dp];
        float r1 = 1.0f / s[n * DD + 2 * dp + 1];
        pp[i] = make_float4(c[n * DD + 2 * dp] * r0,
                            c[n * DD + 2 * dp + 1] * r1, r0, r1);
    }
}

__global__ __launch_bounds__(256, 4)
void wavelet_kernel(const float* __restrict__ x,
                    const float4* __restrict__ pp,
                    float* __restrict__ out, int B, int N) {
    int t = threadIdx.x;
    int lane = t & 63;
    int wv = __builtin_amdgcn_readfirstlane(t >> 6);   // wave-uniform
    int n = blockIdx.y * 64 + lane;                    // lane-private column
    int b0 = (blockIdx.x * 4 + wv) * BSTRIP;           // wave-uniform strip

    const float4* pcol = pp + n;   // pp[dp*N + n], lane-coalesced

    float acc[BSTRIP];
#pragma unroll
    for (int bi = 0; bi < BSTRIP; ++bi) acc[bi] = 1.0f;

#pragma unroll
    for (int h = 0; h < 4; ++h) {          // 4 chunks of 16 d (= overflow group)
        // params for this chunk: VGPR-resident, reused by all 8 b rows
        v2f cp[8], rs[8];
#pragma unroll
        for (int i = 0; i < 8; ++i) {
            float4 q = pcol[(size_t)(h * 8 + i) * N];  // coalesced dwordx4
            cp[i] = (v2f){q.x, q.y};
            rs[i] = (v2f){q.z, q.w};
        }

#pragma unroll
        for (int bi = 0; bi < BSTRIP; ++bi) {
            // x slice: wave-uniform address -> scalar/broadcast loads
            const float4* xq =
                (const float4*)(x + (size_t)(b0 + bi) * DD + h * 16);
            float4 X0 = xq[0];
            float4 X1 = xq[1];
            float4 X2 = xq[2];
            float4 X3 = xq[3];
            float xs[16] = {X0.x, X0.y, X0.z, X0.w,
                            X1.x, X1.y, X1.z, X1.w,
                            X2.x, X2.y, X2.z, X2.w,
                            X3.x, X3.y, X3.z, X3.w};
            v2f p  = {1.0f, 1.0f};
            v2f s2 = {0.0f, 0.0f};
#pragma unroll
            for (int k = 0; k < 8; ++k) {          // 8 d-pairs = 16 d
                v2f xv = {xs[2 * k], xs[2 * k + 1]};
                v2f z = __builtin_elementwise_fma(xv, rs[k], -cp[k]);
                v2f w = z * z;
                p = __builtin_elementwise_fma(-w, p, p);
                s2 += w;
            }
            // exp(-0.5*s) = exp2(-0.72134752*s), one per 16-d group
            acc[bi] *= (p.x * p.y) *
                       __builtin_exp2f(-0.72134752f * (s2.x + s2.y));
        }
    }

    // stores: lanes = consecutive n -> coalesced
#pragma unroll
    for (int bi = 0; bi < BSTRIP; ++bi)
        out[(size_t)(b0 + bi) * N + n] = acc[bi];
}

extern "C" void kernel_launch(void* const* d_in, const int* in_sizes, int n_in,
                              void* d_out, int out_size, void* d_ws, size_t ws_size,
                              hipStream_t stream) {
    const float* x = (const float*)d_in[0];
    const float* c = (const float*)d_in[1];
    const float* s = (const float*)d_in[2];
    float* out = (float*)d_out;

    int B = in_sizes[0] / DD;    // 8192
    int N = in_sizes[1] / DD;    // 512

    float4* pp = (float4*)d_ws;  // (DD/2)*N*16 B = 256 KB

    int total = (DD / 2) * N;
    prep<<<(total + 255) / 256, 256, 0, stream>>>(c, s, pp, N);

    // grid: x = b-strip groups (4 waves x 8 rows = 32 rows/block), y = n/64
    dim3 grid(B / (4 * BSTRIP), N / 64);   // 256 x 8 = 2048 blocks
    wavelet_kernel<<<grid, 256, 0, stream>>>(x, pp, out, B, N);
}